// Round 3
// baseline (9727.603 us; speedup 1.0000x reference)
//
#include <hip/hip_runtime.h>
#include <hip/hip_cooperative_groups.h>
#include <stdint.h>

namespace cg = cooperative_groups;

#define D 512
#define RNUM 8
#define TSTEPS 128

typedef __attribute__((ext_vector_type(8))) short s16x8;
typedef __attribute__((ext_vector_type(4))) float f32x4_t;

#define MFMA16(a, b, c) __builtin_amdgcn_mfma_f32_16x16x32_bf16((a), (b), (c), 0, 0, 0)

// frag-ordered LDS linear index: mt*1024 + ks*512 + q*128 + rr*8  (16-row groups, BK=64)
#define FIDX(mt, ks, q, rr) (((mt) * 1024) + ((ks) * 512) + ((q) * 128) + ((rr) * 8))

__device__ __forceinline__ unsigned short f2bf(float f) {
    union { float f; unsigned int u; } v; v.f = f;
    unsigned int r = (v.u + 0x7FFFu + ((v.u >> 16) & 1u)) >> 16;
    return (unsigned short)r;
}
__device__ __forceinline__ float bf2f(unsigned short u) {
    union { unsigned int i; float f; } v; v.i = ((unsigned int)u) << 16;
    return v.f;
}

// ---------------- precompute ----------------

__global__ void k_convert2(const float* __restrict__ a, const float* __restrict__ b,
                           unsigned short* __restrict__ oa, unsigned short* __restrict__ ob, int n) {
    int i = blockIdx.x * 256 + threadIdx.x;
    if (i < n) { oa[i] = f2bf(a[i]); ob[i] = f2bf(b[i]); }
}

// bcomp[r][g] = b_ih[g] + b_hh[g] + sum_j W_ih[g,j] * b_rel[r,j]
__global__ void k_bcomp(const float* __restrict__ W_ih, const float* __restrict__ b_rel,
                        const float* __restrict__ b_ih, const float* __restrict__ b_hh,
                        float* __restrict__ bcomp) {
    int g = blockIdx.x;
    int t = threadIdx.x;
    __shared__ float wrow[512];
    wrow[t]       = W_ih[(long)g * 512 + t];
    wrow[t + 256] = W_ih[(long)g * 512 + t + 256];
    __syncthreads();
    int r = t >> 5, l = t & 31;
    float s = 0.0f;
    for (int j = l; j < 512; j += 32) s += wrow[j] * b_rel[r * 512 + j];
    for (int off = 16; off; off >>= 1) s += __shfl_down(s, off, 32);
    if (l == 0) bcomp[r * 2048 + g] = s + b_ih[g] + b_hh[g];
}

// wrelT[r][k][j] = bf16(W_rel[r][j][k])
__global__ void k_transpose_wrel(const float* __restrict__ W_rel, unsigned short* __restrict__ wrelT) {
    int kt = blockIdx.x, jt = blockIdx.y, r = blockIdx.z;
    int t = threadIdx.x;
    __shared__ float tile[64][65];
    for (int p = 0; p < 16; ++p) {
        int jl = p * 4 + (t >> 6);
        int kl = t & 63;
        tile[jl][kl] = W_rel[((long)r * 512 + jt * 64 + jl) * 512 + kt * 64 + kl];
    }
    __syncthreads();
    for (int p = 0; p < 16; ++p) {
        int kr = p * 4 + (t >> 6);
        int jc = t & 63;
        wrelT[((long)r * 512 + kt * 64 + kr) * 512 + jt * 64 + jc] = f2bf(tile[jc][kr]);
    }
}

__global__ void k_count(const int* __restrict__ rels, int n, int* __restrict__ cnt) {
    __shared__ int lc[RNUM];
    if (threadIdx.x < RNUM) lc[threadIdx.x] = 0;
    __syncthreads();
    int i = blockIdx.x * 256 + threadIdx.x;
    if (i < n) atomicAdd(&lc[rels[i]], 1);
    __syncthreads();
    if (threadIdx.x < RNUM) atomicAdd(&cnt[threadIdx.x], lc[threadIdx.x]);
}

__global__ void k_offsets(const int* __restrict__ cnt, int* __restrict__ roff, int* __restrict__ cur) {
    int acc = 0;
    for (int r = 0; r < RNUM; ++r) { roff[r] = acc; cur[r] = acc; acc += cnt[r]; }
    roff[RNUM] = acc;
}

__global__ void k_scatter(const int* __restrict__ rels, int n, int* __restrict__ cur, int* __restrict__ perm) {
    __shared__ int lc[RNUM];
    __shared__ int lbase[RNUM];
    if (threadIdx.x < RNUM) lc[threadIdx.x] = 0;
    __syncthreads();
    int i = blockIdx.x * 256 + threadIdx.x;
    int r = 0, lpos = 0;
    bool ok = (i < n);
    if (ok) { r = rels[i]; lpos = atomicAdd(&lc[r], 1); }
    __syncthreads();
    if (threadIdx.x < RNUM) lbase[threadIdx.x] = atomicAdd(&cur[threadIdx.x], lc[threadIdx.x]);
    __syncthreads();
    if (ok) perm[lbase[r] + lpos] = i;
}

// xg[i] = bf16(embed[nodes[perm[i]]])  (permuted order, one wave per row)
__global__ void k_gather_x(const float* __restrict__ embed, const int* __restrict__ nodes,
                           const int* __restrict__ perm, unsigned short* __restrict__ xg, int n_tok) {
    int i = blockIdx.x * 4 + (threadIdx.x >> 6);
    if (i >= n_tok) return;
    int lane = threadIdx.x & 63;
    long node = nodes[perm[i]];
    const float4* src = (const float4*)(embed + node * 512 + lane * 8);
    float4 f0 = src[0], f1 = src[1];
    union { uint4 q; unsigned short u[8]; } v;
    v.u[0] = f2bf(f0.x); v.u[1] = f2bf(f0.y); v.u[2] = f2bf(f0.z); v.u[3] = f2bf(f0.w);
    v.u[4] = f2bf(f1.x); v.u[5] = f2bf(f1.y); v.u[6] = f2bf(f1.z); v.u[7] = f2bf(f1.w);
    *(uint4*)(xg + (long)i * 512 + lane * 8) = v.q;
}

// Wc[r] = W_ih @ W_rel[r]   (2048x512 @ 512x512 -> 2048x512), NT form: B = wrelT
__launch_bounds__(256)
__global__ void k_wcomp(const unsigned short* __restrict__ wih, const unsigned short* __restrict__ wrelT,
                        unsigned short* __restrict__ wc) {
    int r = blockIdx.z;
    int g0 = blockIdx.x * 64, k0 = blockIdx.y * 64;
    __shared__ __align__(16) unsigned short As[4096];
    __shared__ __align__(16) unsigned short Bs[4096];
    int t = threadIdx.x, lane = t & 63, wv = t >> 6;
    int quad = lane >> 4, lrow = lane & 15;
    int wy = wv >> 1, wx = wv & 1;

    int sr = t >> 2, sk = (t & 3) * 16;
    const unsigned short* asrc = wih + (long)(g0 + sr) * 512;
    const unsigned short* bsrc = wrelT + ((long)r * 512 + k0 + sr) * 512;
    int d0 = FIDX(sr >> 4, sk >> 5, (sk >> 3) & 3, sr & 15);

    f32x4_t acc[2][2];
#pragma unroll
    for (int i = 0; i < 2; ++i)
#pragma unroll
        for (int j = 0; j < 2; ++j) acc[i][j] = (f32x4_t)(0.0f);

    for (int kb = 0; kb < 512; kb += 64) {
        __syncthreads();
        *(uint4*)(As + d0)       = *(const uint4*)(asrc + kb + sk);
        *(uint4*)(As + d0 + 128) = *(const uint4*)(asrc + kb + sk + 8);
        *(uint4*)(Bs + d0)       = *(const uint4*)(bsrc + kb + sk);
        *(uint4*)(Bs + d0 + 128) = *(const uint4*)(bsrc + kb + sk + 8);
        __syncthreads();
#pragma unroll
        for (int ks = 0; ks < 2; ++ks) {
            s16x8 a[2], b[2];
#pragma unroll
            for (int i = 0; i < 2; ++i) a[i] = *(const s16x8*)(As + FIDX(wy * 2 + i, ks, quad, lrow));
#pragma unroll
            for (int j = 0; j < 2; ++j) b[j] = *(const s16x8*)(Bs + FIDX(wx * 2 + j, ks, quad, lrow));
#pragma unroll
            for (int i = 0; i < 2; ++i)
#pragma unroll
                for (int j = 0; j < 2; ++j) acc[i][j] = MFMA16(a[i], b[j], acc[i][j]);
        }
    }
#pragma unroll
    for (int i = 0; i < 2; ++i)
#pragma unroll
        for (int j = 0; j < 2; ++j)
#pragma unroll
            for (int rg = 0; rg < 4; ++rg) {
                int g = g0 + (wy * 2 + i) * 16 + quad * 4 + rg;
                int k = k0 + (wx * 2 + j) * 16 + lrow;
                wc[((long)r * 2048 + g) * 512 + k] = f2bf(acc[i][j][rg]);
            }
}

// gx[tok][2048] = xg[i] @ Wc[rel]^T + bcomp[rel]   (bf16 out)
// grid: (16 j-tiles, row-tiles) so j-tiles of one row-tile are adjacent (L2/L3 reuse on xg)
__launch_bounds__(256)
__global__ void k_stageA2(const unsigned short* __restrict__ xg, const unsigned short* __restrict__ wc,
                          const float* __restrict__ bcomp, const int* __restrict__ perm,
                          const int* __restrict__ roff, unsigned short* __restrict__ gx) {
    __shared__ int sroff[RNUM + 1];
    if (threadIdx.x <= RNUM) sroff[threadIdx.x] = roff[threadIdx.x];
    __syncthreads();

    int tb = blockIdx.y;
    int rel = -1, row0 = 0, nrows = 0, acct = 0;
    for (int r = 0; r < RNUM; ++r) {
        int cnt = sroff[r + 1] - sroff[r];
        int tiles = (cnt + 127) >> 7;
        if (tb < acct + tiles) {
            rel = r;
            row0 = sroff[r] + (tb - acct) * 128;
            nrows = sroff[r + 1] - row0;
            if (nrows > 128) nrows = 128;
            break;
        }
        acct += tiles;
    }
    if (rel < 0) return;
    int jbase = blockIdx.x * 128;

    __shared__ __align__(16) unsigned short As[8192];
    __shared__ __align__(16) unsigned short Bs[8192];

    int t = threadIdx.x, lane = t & 63, wv = t >> 6;
    int quad = lane >> 4, lrow = lane & 15;
    int wy = wv >> 1, wx = wv & 1;

    int sr = t >> 1, sk = (t & 1) * 32;
    int arow = (sr < nrows) ? sr : 0;
    const unsigned short* asrc = xg + (long)(row0 + arow) * 512;
    const unsigned short* bsrc = wc + ((long)rel * 2048 + jbase + sr) * 512;
    int d0 = FIDX(sr >> 4, sk >> 5, 0, sr & 15);

    f32x4_t acc[4][4];
#pragma unroll
    for (int i = 0; i < 4; ++i)
#pragma unroll
        for (int j = 0; j < 4; ++j) acc[i][j] = (f32x4_t)(0.0f);

    for (int kb = 0; kb < 512; kb += 64) {
        __syncthreads();
#pragma unroll
        for (int q = 0; q < 4; ++q) {
            *(uint4*)(As + d0 + q * 128) = *(const uint4*)(asrc + kb + sk + q * 8);
            *(uint4*)(Bs + d0 + q * 128) = *(const uint4*)(bsrc + kb + sk + q * 8);
        }
        __syncthreads();
#pragma unroll
        for (int ks = 0; ks < 2; ++ks) {
            s16x8 a[4], b[4];
#pragma unroll
            for (int i = 0; i < 4; ++i) a[i] = *(const s16x8*)(As + FIDX(wy * 4 + i, ks, quad, lrow));
#pragma unroll
            for (int j = 0; j < 4; ++j) b[j] = *(const s16x8*)(Bs + FIDX(wx * 4 + j, ks, quad, lrow));
#pragma unroll
            for (int i = 0; i < 4; ++i)
#pragma unroll
                for (int j = 0; j < 4; ++j) acc[i][j] = MFMA16(a[i], b[j], acc[i][j]);
        }
    }

#pragma unroll
    for (int i = 0; i < 4; ++i)
#pragma unroll
        for (int rg = 0; rg < 4; ++rg) {
            int row = wy * 64 + i * 16 + quad * 4 + rg;
            if (row < nrows) {
                long tok = perm[row0 + row];
#pragma unroll
                for (int j = 0; j < 4; ++j) {
                    int col = jbase + wx * 64 + j * 16 + lrow;
                    gx[tok * 2048 + col] = f2bf(acc[i][j][rg] + bcomp[rel * 2048 + col]);
                }
            }
        }
}

// ---------------- persistent cooperative LSTM scan ----------------
// 256 blocks x 256 threads, one block per CU. Block (rt,jt): rows [rt*128,+128),
// j-cols [jt*16,+16) x 4 gates. W_hh slice resident in LDS (64 KB, frag order).
// c resident in registers. h double-buffered in global. One grid.sync() per step.
__launch_bounds__(256, 1)
__global__ void k_scan(const unsigned short* __restrict__ gx,
                       const unsigned short* __restrict__ whh,
                       unsigned short* __restrict__ h0,
                       unsigned short* __restrict__ h1,
                       float* __restrict__ out) {
    cg::grid_group grid = cg::this_grid();

    int bid = blockIdx.x;
    int rt = bid >> 5;          // 0..7  : row tile (128 rows)
    int jt = bid & 31;          // 0..31 : j tile (16 h-cols)
    int t0 = threadIdx.x, lane = t0 & 63, w = t0 >> 6;
    int quad = lane >> 4, lrow = lane & 15;

    __shared__ __align__(16) unsigned short Bs[32768];  // 64 KB: 4 gates x 16 ks x 64 lanes x 8

    // stage W_hh slice once, frag-ordered
    {
        int g = t0 >> 6, col = (t0 >> 2) & 15, q = t0 & 3;
        const unsigned short* src = whh + ((long)(g * 512 + jt * 16 + col)) * 512 + q * 8;
#pragma unroll
        for (int ks = 0; ks < 16; ++ks) {
            *(uint4*)(Bs + (g * 16 + ks) * 512 + q * 128 + col * 8) = *(const uint4*)(src + ks * 32);
        }
    }
    __syncthreads();

    int rowb = rt * 128 + w * 32;        // wave's 32-row base
    int colg = jt * 16 + lrow;           // this lane's h-column

    float creg[2][4];
#pragma unroll
    for (int m = 0; m < 2; ++m)
#pragma unroll
        for (int rg = 0; rg < 4; ++rg) creg[m][rg] = 0.0f;

    int row0 = 0;
    for (int t = 0; t < TSTEPS; ++t) {
        int bs = 8 * (TSTEPS - t);
        const unsigned short* hin = (t & 1) ? h1 : h0;
        unsigned short* hout = (t & 1) ? h0 : h1;

        if (t) { __threadfence(); grid.sync(); }

        if (rowb < bs) {
            // hoisted gx loads (independent of h) — hide HBM latency under MFMA
            float gxv[2][4][4];
#pragma unroll
            for (int m = 0; m < 2; ++m)
#pragma unroll
                for (int rg = 0; rg < 4; ++rg) {
                    int row = rowb + m * 16 + quad * 4 + rg;
                    bool act = row < bs;
                    long gb = (long)(row0 + (act ? row : 0)) * 2048;
#pragma unroll
                    for (int g = 0; g < 4; ++g)
                        gxv[m][g][rg] = act ? bf2f(gx[gb + g * 512 + colg]) : 0.0f;
                }

            f32x4_t acc[2][4];
#pragma unroll
            for (int m = 0; m < 2; ++m)
#pragma unroll
                for (int g = 0; g < 4; ++g) acc[m][g] = (f32x4_t)(0.0f);

            const unsigned short* a0 = hin + (long)(rowb + lrow) * 512 + quad * 8;
            const unsigned short* a1 = a0 + 16 * 512;
#pragma unroll 4
            for (int ks = 0; ks < 16; ++ks) {
                s16x8 av0 = *(const s16x8*)(a0 + ks * 32);
                s16x8 av1 = *(const s16x8*)(a1 + ks * 32);
#pragma unroll
                for (int g = 0; g < 4; ++g) {
                    s16x8 b = *(const s16x8*)(Bs + (g * 16 + ks) * 512 + lane * 8);
                    acc[0][g] = MFMA16(av0, b, acc[0][g]);
                    acc[1][g] = MFMA16(av1, b, acc[1][g]);
                }
            }

#pragma unroll
            for (int m = 0; m < 2; ++m) {
#pragma unroll
                for (int rg = 0; rg < 4; ++rg) {
                    int row = rowb + m * 16 + quad * 4 + rg;
                    float iv = acc[m][0][rg] + gxv[m][0][rg];
                    float fv = acc[m][1][rg] + gxv[m][1][rg];
                    float gv = acc[m][2][rg] + gxv[m][2][rg];
                    float ov = acc[m][3][rg] + gxv[m][3][rg];
                    float ig = 1.0f / (1.0f + __expf(-iv));
                    float fg = 1.0f / (1.0f + __expf(-fv));
                    float gt = 1.0f - 2.0f / (__expf(2.0f * gv) + 1.0f);
                    float og = 1.0f / (1.0f + __expf(-ov));
                    float cn = fg * creg[m][rg] + ig * gt;
                    creg[m][rg] = cn;
                    float hn = og * (1.0f - 2.0f / (__expf(2.0f * cn) + 1.0f));
                    if (row < bs) {
                        out[(long)(row0 + row) * 512 + colg] = hn;
                        hout[(long)row * 512 + colg] = f2bf(hn);
                    }
                }
            }
        }
        row0 += bs;
    }
}

// ---------------- host ----------------

extern "C" void kernel_launch(void* const* d_in, const int* in_sizes, int n_in,
                              void* d_out, int out_size, void* d_ws, size_t ws_size,
                              hipStream_t stream) {
    const float* embed = (const float*)d_in[0];
    const float* W_rel = (const float*)d_in[1];
    const float* b_rel = (const float*)d_in[2];
    const float* W_ih  = (const float*)d_in[3];
    const float* W_hh  = (const float*)d_in[4];
    const float* b_ih  = (const float*)d_in[5];
    const float* b_hh  = (const float*)d_in[6];
    const int* nodes = (const int*)d_in[7];
    const int* rels  = (const int*)d_in[8];
    int n_tok = in_sizes[7];
    float* out = (float*)d_out;

    char* ws = (char*)d_ws;
    size_t off = 0;
    auto alloc = [&](size_t bytes) -> void* {
        void* p = ws + off;
        off = (off + bytes + 255) & ~(size_t)255;
        return p;
    };
    unsigned short* gx    = (unsigned short*)alloc((size_t)n_tok * 2048 * 2);
    unsigned short* xg    = (unsigned short*)alloc((size_t)n_tok * 512 * 2);
    unsigned short* wih   = (unsigned short*)alloc((size_t)2048 * 512 * 2);
    unsigned short* whh   = (unsigned short*)alloc((size_t)2048 * 512 * 2);
    unsigned short* wrelT = (unsigned short*)alloc((size_t)RNUM * 512 * 512 * 2);
    unsigned short* wc    = (unsigned short*)alloc((size_t)RNUM * 2048 * 512 * 2);
    float* bcomp          = (float*)alloc((size_t)RNUM * 2048 * 4);
    unsigned short* h0    = (unsigned short*)alloc((size_t)1024 * 512 * 2);
    unsigned short* h1    = (unsigned short*)alloc((size_t)1024 * 512 * 2);
    int* perm             = (int*)alloc((size_t)n_tok * 4);
    int* cnt              = (int*)alloc(64);
    int* roff             = (int*)alloc(64);
    int* cur              = (int*)alloc(64);

    if (off > ws_size) return;  // workspace too small: fail loudly (out stays poisoned)

    hipMemsetAsync(cnt, 0, 64, stream);
    hipMemsetAsync(h0, 0, (size_t)1024 * 512 * 2, stream);

    int nw = 2048 * 512;
    k_convert2<<<dim3((nw + 255) / 256), dim3(256), 0, stream>>>(W_ih, W_hh, wih, whh, nw);
    k_bcomp<<<dim3(2048), dim3(256), 0, stream>>>(W_ih, b_rel, b_ih, b_hh, bcomp);
    k_transpose_wrel<<<dim3(8, 8, 8), dim3(256), 0, stream>>>(W_rel, wrelT);

    int nb = (n_tok + 255) / 256;
    k_count<<<dim3(nb), dim3(256), 0, stream>>>(rels, n_tok, cnt);
    k_offsets<<<dim3(1), dim3(1), 0, stream>>>(cnt, roff, cur);
    k_scatter<<<dim3(nb), dim3(256), 0, stream>>>(rels, n_tok, cur, perm);

    k_gather_x<<<dim3((n_tok + 3) / 4), dim3(256), 0, stream>>>(embed, nodes, perm, xg, n_tok);
    k_wcomp<<<dim3(32, 8, 8), dim3(256), 0, stream>>>(wih, wrelT, wc);

    int tilesA = (n_tok + 127) / 128 + RNUM;
    k_stageA2<<<dim3(16, tilesA), dim3(256), 0, stream>>>(xg, wc, bcomp, perm, roff, gx);

    void* args[] = { (void*)&gx, (void*)&whh, (void*)&h0, (void*)&h1, (void*)&out };
    hipLaunchCooperativeKernel((void*)k_scan, dim3(256), dim3(256), args, 0, stream);
}

// Round 4
// 2888.564 us; speedup vs baseline: 3.3676x; 3.3676x over previous
//
#include <hip/hip_runtime.h>
#include <stdint.h>

#define D 512
#define RNUM 8
#define TSTEPS 128

typedef __attribute__((ext_vector_type(8))) short s16x8;
typedef __attribute__((ext_vector_type(4))) float f32x4_t;

#define MFMA16(a, b, c) __builtin_amdgcn_mfma_f32_16x16x32_bf16((a), (b), (c), 0, 0, 0)

// frag-ordered LDS linear index: mt*1024 + ks*512 + q*128 + rr*8  (16-row groups, BK=64)
#define FIDX(mt, ks, q, rr) (((mt) * 1024) + ((ks) * 512) + ((q) * 128) + ((rr) * 8))

__device__ __forceinline__ unsigned short f2bf(float f) {
    union { float f; unsigned int u; } v; v.f = f;
    unsigned int r = (v.u + 0x7FFFu + ((v.u >> 16) & 1u)) >> 16;
    return (unsigned short)r;
}
__device__ __forceinline__ float bf2f(unsigned short u) {
    union { unsigned int i; float f; } v; v.i = ((unsigned int)u) << 16;
    return v.f;
}
// agent-coherent (cross-XCD) accesses: plain loads/stores with sc0|sc1, no cache flushes
__device__ __forceinline__ unsigned int cohload_u32(const unsigned int* p) {
    return __hip_atomic_load(p, __ATOMIC_RELAXED, __HIP_MEMORY_SCOPE_AGENT);
}
__device__ __forceinline__ void cohstore_u32(unsigned int* p, unsigned int v) {
    __hip_atomic_store(p, v, __ATOMIC_RELAXED, __HIP_MEMORY_SCOPE_AGENT);
}

// ---------------- precompute ----------------

__global__ void k_convert2(const float* __restrict__ a, const float* __restrict__ b,
                           unsigned short* __restrict__ oa, unsigned short* __restrict__ ob, int n) {
    int i = blockIdx.x * 256 + threadIdx.x;
    if (i < n) { oa[i] = f2bf(a[i]); ob[i] = f2bf(b[i]); }
}

// bcomp[r][g] = b_ih[g] + b_hh[g] + sum_j W_ih[g,j] * b_rel[r,j]
__global__ void k_bcomp(const float* __restrict__ W_ih, const float* __restrict__ b_rel,
                        const float* __restrict__ b_ih, const float* __restrict__ b_hh,
                        float* __restrict__ bcomp) {
    int g = blockIdx.x;
    int t = threadIdx.x;
    __shared__ float wrow[512];
    wrow[t]       = W_ih[(long)g * 512 + t];
    wrow[t + 256] = W_ih[(long)g * 512 + t + 256];
    __syncthreads();
    int r = t >> 5, l = t & 31;
    float s = 0.0f;
    for (int j = l; j < 512; j += 32) s += wrow[j] * b_rel[r * 512 + j];
    for (int off = 16; off; off >>= 1) s += __shfl_down(s, off, 32);
    if (l == 0) bcomp[r * 2048 + g] = s + b_ih[g] + b_hh[g];
}

// wrelT[r][k][j] = bf16(W_rel[r][j][k])
__global__ void k_transpose_wrel(const float* __restrict__ W_rel, unsigned short* __restrict__ wrelT) {
    int kt = blockIdx.x, jt = blockIdx.y, r = blockIdx.z;
    int t = threadIdx.x;
    __shared__ float tile[64][65];
    for (int p = 0; p < 16; ++p) {
        int jl = p * 4 + (t >> 6);
        int kl = t & 63;
        tile[jl][kl] = W_rel[((long)r * 512 + jt * 64 + jl) * 512 + kt * 64 + kl];
    }
    __syncthreads();
    for (int p = 0; p < 16; ++p) {
        int kr = p * 4 + (t >> 6);
        int jc = t & 63;
        wrelT[((long)r * 512 + kt * 64 + kr) * 512 + jt * 64 + jc] = f2bf(tile[jc][kr]);
    }
}

__global__ void k_count(const int* __restrict__ rels, int n, int* __restrict__ cnt) {
    __shared__ int lc[RNUM];
    if (threadIdx.x < RNUM) lc[threadIdx.x] = 0;
    __syncthreads();
    int i = blockIdx.x * 256 + threadIdx.x;
    if (i < n) atomicAdd(&lc[rels[i]], 1);
    __syncthreads();
    if (threadIdx.x < RNUM) atomicAdd(&cnt[threadIdx.x], lc[threadIdx.x]);
}

__global__ void k_offsets(const int* __restrict__ cnt, int* __restrict__ roff, int* __restrict__ cur) {
    int acc = 0;
    for (int r = 0; r < RNUM; ++r) { roff[r] = acc; cur[r] = acc; acc += cnt[r]; }
    roff[RNUM] = acc;
}

__global__ void k_scatter(const int* __restrict__ rels, int n, int* __restrict__ cur, int* __restrict__ perm) {
    __shared__ int lc[RNUM];
    __shared__ int lbase[RNUM];
    if (threadIdx.x < RNUM) lc[threadIdx.x] = 0;
    __syncthreads();
    int i = blockIdx.x * 256 + threadIdx.x;
    int r = 0, lpos = 0;
    bool ok = (i < n);
    if (ok) { r = rels[i]; lpos = atomicAdd(&lc[r], 1); }
    __syncthreads();
    if (threadIdx.x < RNUM) lbase[threadIdx.x] = atomicAdd(&cur[threadIdx.x], lc[threadIdx.x]);
    __syncthreads();
    if (ok) perm[lbase[r] + lpos] = i;
}

// xg[i] = bf16(embed[nodes[perm[i]]])  (permuted order, one wave per row)
__global__ void k_gather_x(const float* __restrict__ embed, const int* __restrict__ nodes,
                           const int* __restrict__ perm, unsigned short* __restrict__ xg, int n_tok) {
    int i = blockIdx.x * 4 + (threadIdx.x >> 6);
    if (i >= n_tok) return;
    int lane = threadIdx.x & 63;
    long node = nodes[perm[i]];
    const float4* src = (const float4*)(embed + node * 512 + lane * 8);
    float4 f0 = src[0], f1 = src[1];
    union { uint4 q; unsigned short u[8]; } v;
    v.u[0] = f2bf(f0.x); v.u[1] = f2bf(f0.y); v.u[2] = f2bf(f0.z); v.u[3] = f2bf(f0.w);
    v.u[4] = f2bf(f1.x); v.u[5] = f2bf(f1.y); v.u[6] = f2bf(f1.z); v.u[7] = f2bf(f1.w);
    *(uint4*)(xg + (long)i * 512 + lane * 8) = v.q;
}

// Wc[r] = W_ih @ W_rel[r]   (2048x512 @ 512x512 -> 2048x512), NT form: B = wrelT
__launch_bounds__(256)
__global__ void k_wcomp(const unsigned short* __restrict__ wih, const unsigned short* __restrict__ wrelT,
                        unsigned short* __restrict__ wc) {
    int r = blockIdx.z;
    int g0 = blockIdx.x * 64, k0 = blockIdx.y * 64;
    __shared__ __align__(16) unsigned short As[4096];
    __shared__ __align__(16) unsigned short Bs[4096];
    int t = threadIdx.x, lane = t & 63, wv = t >> 6;
    int quad = lane >> 4, lrow = lane & 15;
    int wy = wv >> 1, wx = wv & 1;

    int sr = t >> 2, sk = (t & 3) * 16;
    const unsigned short* asrc = wih + (long)(g0 + sr) * 512;
    const unsigned short* bsrc = wrelT + ((long)r * 512 + k0 + sr) * 512;
    int d0 = FIDX(sr >> 4, sk >> 5, (sk >> 3) & 3, sr & 15);

    f32x4_t acc[2][2];
#pragma unroll
    for (int i = 0; i < 2; ++i)
#pragma unroll
        for (int j = 0; j < 2; ++j) acc[i][j] = (f32x4_t)(0.0f);

    for (int kb = 0; kb < 512; kb += 64) {
        __syncthreads();
        *(uint4*)(As + d0)       = *(const uint4*)(asrc + kb + sk);
        *(uint4*)(As + d0 + 128) = *(const uint4*)(asrc + kb + sk + 8);
        *(uint4*)(Bs + d0)       = *(const uint4*)(bsrc + kb + sk);
        *(uint4*)(Bs + d0 + 128) = *(const uint4*)(bsrc + kb + sk + 8);
        __syncthreads();
#pragma unroll
        for (int ks = 0; ks < 2; ++ks) {
            s16x8 a[2], b[2];
#pragma unroll
            for (int i = 0; i < 2; ++i) a[i] = *(const s16x8*)(As + FIDX(wy * 2 + i, ks, quad, lrow));
#pragma unroll
            for (int j = 0; j < 2; ++j) b[j] = *(const s16x8*)(Bs + FIDX(wx * 2 + j, ks, quad, lrow));
#pragma unroll
            for (int i = 0; i < 2; ++i)
#pragma unroll
                for (int j = 0; j < 2; ++j) acc[i][j] = MFMA16(a[i], b[j], acc[i][j]);
        }
    }
#pragma unroll
    for (int i = 0; i < 2; ++i)
#pragma unroll
        for (int j = 0; j < 2; ++j)
#pragma unroll
            for (int rg = 0; rg < 4; ++rg) {
                int g = g0 + (wy * 2 + i) * 16 + quad * 4 + rg;
                int k = k0 + (wx * 2 + j) * 16 + lrow;
                wc[((long)r * 2048 + g) * 512 + k] = f2bf(acc[i][j][rg]);
            }
}

// gx[tok][2048] = xg[i] @ Wc[rel]^T + bcomp[rel]   (bf16 out)
__launch_bounds__(256)
__global__ void k_stageA2(const unsigned short* __restrict__ xg, const unsigned short* __restrict__ wc,
                          const float* __restrict__ bcomp, const int* __restrict__ perm,
                          const int* __restrict__ roff, unsigned short* __restrict__ gx) {
    __shared__ int sroff[RNUM + 1];
    if (threadIdx.x <= RNUM) sroff[threadIdx.x] = roff[threadIdx.x];
    __syncthreads();

    int tb = blockIdx.y;
    int rel = -1, row0 = 0, nrows = 0, acct = 0;
    for (int r = 0; r < RNUM; ++r) {
        int cnt = sroff[r + 1] - sroff[r];
        int tiles = (cnt + 127) >> 7;
        if (tb < acct + tiles) {
            rel = r;
            row0 = sroff[r] + (tb - acct) * 128;
            nrows = sroff[r + 1] - row0;
            if (nrows > 128) nrows = 128;
            break;
        }
        acct += tiles;
    }
    if (rel < 0) return;
    int jbase = blockIdx.x * 128;

    __shared__ __align__(16) unsigned short As[8192];
    __shared__ __align__(16) unsigned short Bs[8192];

    int t = threadIdx.x, lane = t & 63, wv = t >> 6;
    int quad = lane >> 4, lrow = lane & 15;
    int wy = wv >> 1, wx = wv & 1;

    int sr = t >> 1, sk = (t & 1) * 32;
    int arow = (sr < nrows) ? sr : 0;
    const unsigned short* asrc = xg + (long)(row0 + arow) * 512;
    const unsigned short* bsrc = wc + ((long)rel * 2048 + jbase + sr) * 512;
    int d0 = FIDX(sr >> 4, sk >> 5, 0, sr & 15);

    f32x4_t acc[4][4];
#pragma unroll
    for (int i = 0; i < 4; ++i)
#pragma unroll
        for (int j = 0; j < 4; ++j) acc[i][j] = (f32x4_t)(0.0f);

    for (int kb = 0; kb < 512; kb += 64) {
        __syncthreads();
#pragma unroll
        for (int q = 0; q < 4; ++q) {
            *(uint4*)(As + d0 + q * 128) = *(const uint4*)(asrc + kb + sk + q * 8);
            *(uint4*)(Bs + d0 + q * 128) = *(const uint4*)(bsrc + kb + sk + q * 8);
        }
        __syncthreads();
#pragma unroll
        for (int ks = 0; ks < 2; ++ks) {
            s16x8 a[4], b[4];
#pragma unroll
            for (int i = 0; i < 4; ++i) a[i] = *(const s16x8*)(As + FIDX(wy * 4 + i, ks, quad, lrow));
#pragma unroll
            for (int j = 0; j < 4; ++j) b[j] = *(const s16x8*)(Bs + FIDX(wx * 4 + j, ks, quad, lrow));
#pragma unroll
            for (int i = 0; i < 4; ++i)
#pragma unroll
                for (int j = 0; j < 4; ++j) acc[i][j] = MFMA16(a[i], b[j], acc[i][j]);
        }
    }

#pragma unroll
    for (int i = 0; i < 4; ++i)
#pragma unroll
        for (int rg = 0; rg < 4; ++rg) {
            int row = wy * 64 + i * 16 + quad * 4 + rg;
            if (row < nrows) {
                long tok = perm[row0 + row];
#pragma unroll
                for (int j = 0; j < 4; ++j) {
                    int col = jbase + wx * 64 + j * 16 + lrow;
                    gx[tok * 2048 + col] = f2bf(acc[i][j][rg] + bcomp[rel * 2048 + col]);
                }
            }
        }
}

// ---------------- group-parallel persistent LSTM scan ----------------
// 256 blocks: group = bid>>5 (rows [128g,128g+128)), jt = bid&31 (16 h-cols x 4 gates).
// Rows are independent across groups -> only 32-block intra-group barriers.
// W_hh slice resident in LDS (64 KB). c in registers. h double-buffered in global,
// accessed via relaxed agent-scope atomics (sc0|sc1, no cache flushes).
__launch_bounds__(256, 1)
__global__ void k_scan_grp(const unsigned short* __restrict__ gx,
                           const unsigned short* __restrict__ whh,
                           unsigned short* __restrict__ hb0,
                           unsigned short* __restrict__ hb1,
                           float* __restrict__ out,
                           int* __restrict__ bars) {
    int bid = blockIdx.x;
    int grp = bid >> 5;
    int jt  = bid & 31;
    int tid = threadIdx.x, lane = tid & 63, w = tid >> 6;
    int quad = lane >> 4, lrow = lane & 15;

    __shared__ __align__(16) unsigned short Bs[32768];  // 64 KB W_hh slice, frag-ordered
    {
        int g = tid >> 6, col = (tid >> 2) & 15, q = tid & 3;
        const unsigned short* src = whh + ((long)(g * 512 + jt * 16 + col)) * 512 + q * 8;
#pragma unroll
        for (int ks = 0; ks < 16; ++ks)
            *(uint4*)(Bs + (g * 16 + ks) * 512 + q * 128 + col * 8) = *(const uint4*)(src + ks * 32);
    }
    __syncthreads();

    int tmax = 128 - 16 * grp;      // max seq length within this group's rows
    int rowl = w * 32;              // wave's local row base (0..96)
    int colg = jt * 16 + lrow;      // this lane's h-column
    int* bar = bars + grp * 64;     // per-group barrier counter (256 B apart)

    float creg[2][4];
#pragma unroll
    for (int m = 0; m < 2; ++m)
#pragma unroll
        for (int rg = 0; rg < 4; ++rg) creg[m][rg] = 0.0f;

    for (int t = 0; t < tmax; ++t) {
        int local_bs = 8 * (128 - t) - grp * 128;
        if (local_bs > 128) local_bs = 128;
        long tok0 = 4L * t * (257 - t) + grp * 128;     // token idx of this group's row 0
        const unsigned int* hr = (const unsigned int*)((t & 1) ? hb1 : hb0);
        unsigned int* hw = (unsigned int*)((t & 1) ? hb0 : hb1);
        bool wact = rowl < local_bs;

        // gx prefetch for this step (read-only, cached) — issued before the barrier spin
        unsigned int gxr[2][4][4];
        if (wact) {
#pragma unroll
            for (int m = 0; m < 2; ++m)
#pragma unroll
                for (int rg = 0; rg < 4; ++rg) {
                    int row = rowl + m * 16 + quad * 4 + rg;
                    bool act = row < local_bs;
                    long gb = (tok0 + row) * 2048;
#pragma unroll
                    for (int g = 0; g < 4; ++g)
                        gxr[m][g][rg] = act ? (unsigned int)gx[gb + g * 512 + colg] : 0u;
                }
        }

        // wait: all 32 group blocks finished step t-1
        if (t > 0) {
            if (tid == 0) {
                int target = 32 * t;
                while (__hip_atomic_load(bar, __ATOMIC_RELAXED, __HIP_MEMORY_SCOPE_AGENT) < target)
                    __builtin_amdgcn_s_sleep(1);
            }
            __syncthreads();
            asm volatile("" ::: "memory");
        }

        f32x4_t acc[2][4];
#pragma unroll
        for (int m = 0; m < 2; ++m)
#pragma unroll
            for (int g = 0; g < 4; ++g) acc[m][g] = (f32x4_t)(0.0f);

        if (t > 0 && wact) {
            const unsigned int* a0 = hr + (long)(grp * 128 + rowl + lrow) * 256 + quad * 4;
            const unsigned int* a1 = a0 + 16 * 256;
            unsigned int ar[2][2][4][4];   // [slot][m][ks-in-chunk][dword]
#pragma unroll
            for (int ksl = 0; ksl < 4; ++ksl)
#pragma unroll
                for (int dw = 0; dw < 4; ++dw) {
                    ar[0][0][ksl][dw] = cohload_u32(a0 + ksl * 16 + dw);
                    ar[0][1][ksl][dw] = cohload_u32(a1 + ksl * 16 + dw);
                }
#pragma unroll
            for (int c = 0; c < 4; ++c) {
                if (c < 3) {
#pragma unroll
                    for (int ksl = 0; ksl < 4; ++ksl)
#pragma unroll
                        for (int dw = 0; dw < 4; ++dw) {
                            ar[(c + 1) & 1][0][ksl][dw] = cohload_u32(a0 + (c + 1) * 64 + ksl * 16 + dw);
                            ar[(c + 1) & 1][1][ksl][dw] = cohload_u32(a1 + (c + 1) * 64 + ksl * 16 + dw);
                        }
                }
#pragma unroll
                for (int ksl = 0; ksl < 4; ++ksl) {
                    int ks = c * 4 + ksl;
                    s16x8 av0 = *(const s16x8*)&ar[c & 1][0][ksl][0];
                    s16x8 av1 = *(const s16x8*)&ar[c & 1][1][ksl][0];
#pragma unroll
                    for (int g = 0; g < 4; ++g) {
                        s16x8 b = *(const s16x8*)(Bs + (g * 16 + ks) * 512 + lane * 8);
                        acc[0][g] = MFMA16(av0, b, acc[0][g]);
                        acc[1][g] = MFMA16(av1, b, acc[1][g]);
                    }
                }
            }
        }

        if (wact) {
#pragma unroll
            for (int m = 0; m < 2; ++m) {
#pragma unroll
                for (int rg = 0; rg < 4; ++rg) {
                    int row = rowl + m * 16 + quad * 4 + rg;
                    float iv = acc[m][0][rg] + bf2f((unsigned short)gxr[m][0][rg]);
                    float fv = acc[m][1][rg] + bf2f((unsigned short)gxr[m][1][rg]);
                    float gv = acc[m][2][rg] + bf2f((unsigned short)gxr[m][2][rg]);
                    float ov = acc[m][3][rg] + bf2f((unsigned short)gxr[m][3][rg]);
                    float ig = 1.0f / (1.0f + __expf(-iv));
                    float fg = 1.0f / (1.0f + __expf(-fv));
                    float gt = 1.0f - 2.0f / (__expf(2.0f * gv) + 1.0f);
                    float og = 1.0f / (1.0f + __expf(-ov));
                    float cn = fg * creg[m][rg] + ig * gt;
                    creg[m][rg] = cn;
                    float hn = og * (1.0f - 2.0f / (__expf(2.0f * cn) + 1.0f));
                    if (row < local_bs) out[(tok0 + row) * 512 + colg] = hn;
                    // pack lane-pair (adjacent cols, same rows) into one u32 coherent store
                    unsigned int hv = (unsigned int)f2bf(hn);
                    unsigned int ov2 = (unsigned int)__shfl_xor((int)hv, 1, 64);
                    unsigned int hpair = (lane & 1) ? ((hv << 16) | ov2) : (hv | (ov2 << 16));
                    if (((lane & 1) == m) && (row < local_bs))
                        cohstore_u32(hw + (long)(grp * 128 + row) * 256 + jt * 8 + (lrow >> 1), hpair);
                }
            }
        }

        // arrive: h stores drained, then one relaxed RMW per block
        if (t < tmax - 1) {
            asm volatile("s_waitcnt vmcnt(0)" ::: "memory");
            __syncthreads();
            if (tid == 0)
                __hip_atomic_fetch_add(bar, 1, __ATOMIC_RELAXED, __HIP_MEMORY_SCOPE_AGENT);
        }
    }
}

// ---------------- host ----------------

extern "C" void kernel_launch(void* const* d_in, const int* in_sizes, int n_in,
                              void* d_out, int out_size, void* d_ws, size_t ws_size,
                              hipStream_t stream) {
    const float* embed = (const float*)d_in[0];
    const float* W_rel = (const float*)d_in[1];
    const float* b_rel = (const float*)d_in[2];
    const float* W_ih  = (const float*)d_in[3];
    const float* W_hh  = (const float*)d_in[4];
    const float* b_ih  = (const float*)d_in[5];
    const float* b_hh  = (const float*)d_in[6];
    const int* nodes = (const int*)d_in[7];
    const int* rels  = (const int*)d_in[8];
    int n_tok = in_sizes[7];
    float* out = (float*)d_out;

    char* ws = (char*)d_ws;
    size_t off = 0;
    auto alloc = [&](size_t bytes) -> void* {
        void* p = ws + off;
        off = (off + bytes + 255) & ~(size_t)255;
        return p;
    };
    unsigned short* gx    = (unsigned short*)alloc((size_t)n_tok * 2048 * 2);
    unsigned short* xg    = (unsigned short*)alloc((size_t)n_tok * 512 * 2);
    unsigned short* wih   = (unsigned short*)alloc((size_t)2048 * 512 * 2);
    unsigned short* whh   = (unsigned short*)alloc((size_t)2048 * 512 * 2);
    unsigned short* wrelT = (unsigned short*)alloc((size_t)RNUM * 512 * 512 * 2);
    unsigned short* wc    = (unsigned short*)alloc((size_t)RNUM * 2048 * 512 * 2);
    float* bcomp          = (float*)alloc((size_t)RNUM * 2048 * 4);
    unsigned short* h0    = (unsigned short*)alloc((size_t)1024 * 512 * 2);
    unsigned short* h1    = (unsigned short*)alloc((size_t)1024 * 512 * 2);
    int* perm             = (int*)alloc((size_t)n_tok * 4);
    int* bars             = (int*)alloc(RNUM * 64 * 4);
    int* cnt              = (int*)alloc(64);
    int* roff             = (int*)alloc(64);
    int* cur              = (int*)alloc(64);

    if (off > ws_size) return;  // workspace too small: fail loudly (out stays poisoned)

    hipMemsetAsync(cnt, 0, 64, stream);
    hipMemsetAsync(bars, 0, RNUM * 64 * 4, stream);

    int nw = 2048 * 512;
    k_convert2<<<dim3((nw + 255) / 256), dim3(256), 0, stream>>>(W_ih, W_hh, wih, whh, nw);
    k_bcomp<<<dim3(2048), dim3(256), 0, stream>>>(W_ih, b_rel, b_ih, b_hh, bcomp);
    k_transpose_wrel<<<dim3(8, 8, 8), dim3(256), 0, stream>>>(W_rel, wrelT);

    int nb = (n_tok + 255) / 256;
    k_count<<<dim3(nb), dim3(256), 0, stream>>>(rels, n_tok, cnt);
    k_offsets<<<dim3(1), dim3(1), 0, stream>>>(cnt, roff, cur);
    k_scatter<<<dim3(nb), dim3(256), 0, stream>>>(rels, n_tok, cur, perm);

    k_gather_x<<<dim3((n_tok + 3) / 4), dim3(256), 0, stream>>>(embed, nodes, perm, xg, n_tok);
    k_wcomp<<<dim3(32, 8, 8), dim3(256), 0, stream>>>(wih, wrelT, wc);

    int tilesA = (n_tok + 127) / 128 + RNUM;
    k_stageA2<<<dim3(16, tilesA), dim3(256), 0, stream>>>(xg, wc, bcomp, perm, roff, gx);

    k_scan_grp<<<dim3(256), dim3(256), 0, stream>>>(gx, whh, h0, h1, out, bars);
}

// Round 5
// 1767.119 us; speedup vs baseline: 5.5048x; 1.6346x over previous
//
#include <hip/hip_runtime.h>
#include <stdint.h>

#define D 512
#define RNUM 8
#define TSTEPS 128

typedef __attribute__((ext_vector_type(8))) short s16x8;
typedef __attribute__((ext_vector_type(4))) float f32x4_t;
typedef __attribute__((ext_vector_type(4))) int v4i;

#define MFMA16(a, b, c) __builtin_amdgcn_mfma_f32_16x16x32_bf16((a), (b), (c), 0, 0, 0)

// frag-ordered LDS linear index: mt*1024 + ks*512 + q*128 + rr*8  (16-row groups, BK=64)
#define FIDX(mt, ks, q, rr) (((mt) * 1024) + ((ks) * 512) + ((q) * 128) + ((rr) * 8))

// raw MUBUF ops with explicit cache policy (CPol bit0=sc0, bit4=sc1 on gfx940+)
extern "C" __device__ v4i llvm_amdgcn_raw_buffer_load_v4i32(v4i rsrc, int voffset, int soffset, int cpol)
    __asm("llvm.amdgcn.raw.buffer.load.v4i32");
extern "C" __device__ void llvm_amdgcn_raw_buffer_store_i32(int vdata, v4i rsrc, int voffset, int soffset, int cpol)
    __asm("llvm.amdgcn.raw.buffer.store.i32");
#define CPOL_COH 17   // sc0|sc1: bypass L1 + per-XCD L2 -> device-coherent, but coalescable

__device__ __forceinline__ v4i make_srd(const void* base) {
    v4i r;
    unsigned long long a = (unsigned long long)base;
    r.x = (int)(a & 0xFFFFFFFFull);
    r.y = (int)(a >> 32);      // stride = 0
    r.z = -1;                  // num_records = 0xFFFFFFFF (bounds check off)
    r.w = 0x00020000;          // raw untyped dword config
    return r;
}

__device__ __forceinline__ unsigned short f2bf(float f) {
    union { float f; unsigned int u; } v; v.f = f;
    unsigned int r = (v.u + 0x7FFFu + ((v.u >> 16) & 1u)) >> 16;
    return (unsigned short)r;
}
__device__ __forceinline__ float bf2f(unsigned short u) {
    union { unsigned int i; float f; } v; v.i = ((unsigned int)u) << 16;
    return v.f;
}

// ---------------- precompute ----------------

__global__ void k_convert2(const float* __restrict__ a, const float* __restrict__ b,
                           unsigned short* __restrict__ oa, unsigned short* __restrict__ ob, int n) {
    int i = blockIdx.x * 256 + threadIdx.x;
    if (i < n) { oa[i] = f2bf(a[i]); ob[i] = f2bf(b[i]); }
}

// bcomp[r][g] = b_ih[g] + b_hh[g] + sum_j W_ih[g,j] * b_rel[r,j]
__global__ void k_bcomp(const float* __restrict__ W_ih, const float* __restrict__ b_rel,
                        const float* __restrict__ b_ih, const float* __restrict__ b_hh,
                        float* __restrict__ bcomp) {
    int g = blockIdx.x;
    int t = threadIdx.x;
    __shared__ float wrow[512];
    wrow[t]       = W_ih[(long)g * 512 + t];
    wrow[t + 256] = W_ih[(long)g * 512 + t + 256];
    __syncthreads();
    int r = t >> 5, l = t & 31;
    float s = 0.0f;
    for (int j = l; j < 512; j += 32) s += wrow[j] * b_rel[r * 512 + j];
    for (int off = 16; off; off >>= 1) s += __shfl_down(s, off, 32);
    if (l == 0) bcomp[r * 2048 + g] = s + b_ih[g] + b_hh[g];
}

// wrelT[r][k][j] = bf16(W_rel[r][j][k])
__global__ void k_transpose_wrel(const float* __restrict__ W_rel, unsigned short* __restrict__ wrelT) {
    int kt = blockIdx.x, jt = blockIdx.y, r = blockIdx.z;
    int t = threadIdx.x;
    __shared__ float tile[64][65];
    for (int p = 0; p < 16; ++p) {
        int jl = p * 4 + (t >> 6);
        int kl = t & 63;
        tile[jl][kl] = W_rel[((long)r * 512 + jt * 64 + jl) * 512 + kt * 64 + kl];
    }
    __syncthreads();
    for (int p = 0; p < 16; ++p) {
        int kr = p * 4 + (t >> 6);
        int jc = t & 63;
        wrelT[((long)r * 512 + kt * 64 + kr) * 512 + jt * 64 + jc] = f2bf(tile[jc][kr]);
    }
}

__global__ void k_count(const int* __restrict__ rels, int n, int* __restrict__ cnt) {
    __shared__ int lc[RNUM];
    if (threadIdx.x < RNUM) lc[threadIdx.x] = 0;
    __syncthreads();
    int i = blockIdx.x * 256 + threadIdx.x;
    if (i < n) atomicAdd(&lc[rels[i]], 1);
    __syncthreads();
    if (threadIdx.x < RNUM) atomicAdd(&cnt[threadIdx.x], lc[threadIdx.x]);
}

__global__ void k_offsets(const int* __restrict__ cnt, int* __restrict__ roff, int* __restrict__ cur) {
    int acc = 0;
    for (int r = 0; r < RNUM; ++r) { roff[r] = acc; cur[r] = acc; acc += cnt[r]; }
    roff[RNUM] = acc;
}

__global__ void k_scatter(const int* __restrict__ rels, int n, int* __restrict__ cur, int* __restrict__ perm) {
    __shared__ int lc[RNUM];
    __shared__ int lbase[RNUM];
    if (threadIdx.x < RNUM) lc[threadIdx.x] = 0;
    __syncthreads();
    int i = blockIdx.x * 256 + threadIdx.x;
    int r = 0, lpos = 0;
    bool ok = (i < n);
    if (ok) { r = rels[i]; lpos = atomicAdd(&lc[r], 1); }
    __syncthreads();
    if (threadIdx.x < RNUM) lbase[threadIdx.x] = atomicAdd(&cur[threadIdx.x], lc[threadIdx.x]);
    __syncthreads();
    if (ok) perm[lbase[r] + lpos] = i;
}

// xg[i] = bf16(embed[nodes[perm[i]]])  (permuted order, one wave per row)
__global__ void k_gather_x(const float* __restrict__ embed, const int* __restrict__ nodes,
                           const int* __restrict__ perm, unsigned short* __restrict__ xg, int n_tok) {
    int i = blockIdx.x * 4 + (threadIdx.x >> 6);
    if (i >= n_tok) return;
    int lane = threadIdx.x & 63;
    long node = nodes[perm[i]];
    const float4* src = (const float4*)(embed + node * 512 + lane * 8);
    float4 f0 = src[0], f1 = src[1];
    union { uint4 q; unsigned short u[8]; } v;
    v.u[0] = f2bf(f0.x); v.u[1] = f2bf(f0.y); v.u[2] = f2bf(f0.z); v.u[3] = f2bf(f0.w);
    v.u[4] = f2bf(f1.x); v.u[5] = f2bf(f1.y); v.u[6] = f2bf(f1.z); v.u[7] = f2bf(f1.w);
    *(uint4*)(xg + (long)i * 512 + lane * 8) = v.q;
}

// Wc[r] = W_ih @ W_rel[r]   (2048x512 @ 512x512 -> 2048x512), NT form: B = wrelT
__launch_bounds__(256)
__global__ void k_wcomp(const unsigned short* __restrict__ wih, const unsigned short* __restrict__ wrelT,
                        unsigned short* __restrict__ wc) {
    int r = blockIdx.z;
    int g0 = blockIdx.x * 64, k0 = blockIdx.y * 64;
    __shared__ __align__(16) unsigned short As[4096];
    __shared__ __align__(16) unsigned short Bs[4096];
    int t = threadIdx.x, lane = t & 63, wv = t >> 6;
    int quad = lane >> 4, lrow = lane & 15;
    int wy = wv >> 1, wx = wv & 1;

    int sr = t >> 2, sk = (t & 3) * 16;
    const unsigned short* asrc = wih + (long)(g0 + sr) * 512;
    const unsigned short* bsrc = wrelT + ((long)r * 512 + k0 + sr) * 512;
    int d0 = FIDX(sr >> 4, sk >> 5, (sk >> 3) & 3, sr & 15);

    f32x4_t acc[2][2];
#pragma unroll
    for (int i = 0; i < 2; ++i)
#pragma unroll
        for (int j = 0; j < 2; ++j) acc[i][j] = (f32x4_t)(0.0f);

    for (int kb = 0; kb < 512; kb += 64) {
        __syncthreads();
        *(uint4*)(As + d0)       = *(const uint4*)(asrc + kb + sk);
        *(uint4*)(As + d0 + 128) = *(const uint4*)(asrc + kb + sk + 8);
        *(uint4*)(Bs + d0)       = *(const uint4*)(bsrc + kb + sk);
        *(uint4*)(Bs + d0 + 128) = *(const uint4*)(bsrc + kb + sk + 8);
        __syncthreads();
#pragma unroll
        for (int ks = 0; ks < 2; ++ks) {
            s16x8 a[2], b[2];
#pragma unroll
            for (int i = 0; i < 2; ++i) a[i] = *(const s16x8*)(As + FIDX(wy * 2 + i, ks, quad, lrow));
#pragma unroll
            for (int j = 0; j < 2; ++j) b[j] = *(const s16x8*)(Bs + FIDX(wx * 2 + j, ks, quad, lrow));
#pragma unroll
            for (int i = 0; i < 2; ++i)
#pragma unroll
                for (int j = 0; j < 2; ++j) acc[i][j] = MFMA16(a[i], b[j], acc[i][j]);
        }
    }
#pragma unroll
    for (int i = 0; i < 2; ++i)
#pragma unroll
        for (int j = 0; j < 2; ++j)
#pragma unroll
            for (int rg = 0; rg < 4; ++rg) {
                int g = g0 + (wy * 2 + i) * 16 + quad * 4 + rg;
                int k = k0 + (wx * 2 + j) * 16 + lrow;
                wc[((long)r * 2048 + g) * 512 + k] = f2bf(acc[i][j][rg]);
            }
}

// gx[tok][2048] = xg[i] @ Wc[rel]^T + bcomp[rel]   (bf16 out)
__launch_bounds__(256)
__global__ void k_stageA2(const unsigned short* __restrict__ xg, const unsigned short* __restrict__ wc,
                          const float* __restrict__ bcomp, const int* __restrict__ perm,
                          const int* __restrict__ roff, unsigned short* __restrict__ gx) {
    __shared__ int sroff[RNUM + 1];
    if (threadIdx.x <= RNUM) sroff[threadIdx.x] = roff[threadIdx.x];
    __syncthreads();

    int tb = blockIdx.y;
    int rel = -1, row0 = 0, nrows = 0, acct = 0;
    for (int r = 0; r < RNUM; ++r) {
        int cnt = sroff[r + 1] - sroff[r];
        int tiles = (cnt + 127) >> 7;
        if (tb < acct + tiles) {
            rel = r;
            row0 = sroff[r] + (tb - acct) * 128;
            nrows = sroff[r + 1] - row0;
            if (nrows > 128) nrows = 128;
            break;
        }
        acct += tiles;
    }
    if (rel < 0) return;
    int jbase = blockIdx.x * 128;

    __shared__ __align__(16) unsigned short As[8192];
    __shared__ __align__(16) unsigned short Bs[8192];

    int t = threadIdx.x, lane = t & 63, wv = t >> 6;
    int quad = lane >> 4, lrow = lane & 15;
    int wy = wv >> 1, wx = wv & 1;

    int sr = t >> 1, sk = (t & 1) * 32;
    int arow = (sr < nrows) ? sr : 0;
    const unsigned short* asrc = xg + (long)(row0 + arow) * 512;
    const unsigned short* bsrc = wc + ((long)rel * 2048 + jbase + sr) * 512;
    int d0 = FIDX(sr >> 4, sk >> 5, 0, sr & 15);

    f32x4_t acc[4][4];
#pragma unroll
    for (int i = 0; i < 4; ++i)
#pragma unroll
        for (int j = 0; j < 4; ++j) acc[i][j] = (f32x4_t)(0.0f);

    for (int kb = 0; kb < 512; kb += 64) {
        __syncthreads();
#pragma unroll
        for (int q = 0; q < 4; ++q) {
            *(uint4*)(As + d0 + q * 128) = *(const uint4*)(asrc + kb + sk + q * 8);
            *(uint4*)(Bs + d0 + q * 128) = *(const uint4*)(bsrc + kb + sk + q * 8);
        }
        __syncthreads();
#pragma unroll
        for (int ks = 0; ks < 2; ++ks) {
            s16x8 a[4], b[4];
#pragma unroll
            for (int i = 0; i < 4; ++i) a[i] = *(const s16x8*)(As + FIDX(wy * 4 + i, ks, quad, lrow));
#pragma unroll
            for (int j = 0; j < 4; ++j) b[j] = *(const s16x8*)(Bs + FIDX(wx * 4 + j, ks, quad, lrow));
#pragma unroll
            for (int i = 0; i < 4; ++i)
#pragma unroll
                for (int j = 0; j < 4; ++j) acc[i][j] = MFMA16(a[i], b[j], acc[i][j]);
        }
    }

#pragma unroll
    for (int i = 0; i < 4; ++i)
#pragma unroll
        for (int rg = 0; rg < 4; ++rg) {
            int row = wy * 64 + i * 16 + quad * 4 + rg;
            if (row < nrows) {
                long tok = perm[row0 + row];
#pragma unroll
                for (int j = 0; j < 4; ++j) {
                    int col = jbase + wx * 64 + j * 16 + lrow;
                    gx[tok * 2048 + col] = f2bf(acc[i][j][rg] + bcomp[rel * 2048 + col]);
                }
            }
        }
}

// ---------------- group-parallel persistent LSTM scan ----------------
// 256 blocks: group = bid>>5 (rows [128g,128g+128)), jt = bid&31 (16 h-cols x 4 gates).
// W_hh slice resident in LDS (64 KB). c in registers. h double-buffered in global,
// accessed via buffer_load_dwordx4 / buffer_store_dword with sc0|sc1 (device-coherent,
// bypass L1+XCD-L2, but COALESCABLE unlike atomic u32 loads — 4x fewer fabric ops).
__launch_bounds__(256, 1)
__global__ void k_scan_grp(const unsigned short* __restrict__ gx,
                           const unsigned short* __restrict__ whh,
                           unsigned short* __restrict__ hb0,
                           unsigned short* __restrict__ hb1,
                           float* __restrict__ out,
                           int* __restrict__ bars) {
    int bid = blockIdx.x;
    int grp = bid >> 5;
    int jt  = bid & 31;
    int tid = threadIdx.x, lane = tid & 63, w = tid >> 6;
    int quad = lane >> 4, lrow = lane & 15;

    __shared__ __align__(16) unsigned short Bs[32768];  // 64 KB W_hh slice, frag-ordered
    {
        int g = tid >> 6, col = (tid >> 2) & 15, q = tid & 3;
        const unsigned short* src = whh + ((long)(g * 512 + jt * 16 + col)) * 512 + q * 8;
#pragma unroll
        for (int ks = 0; ks < 16; ++ks)
            *(uint4*)(Bs + (g * 16 + ks) * 512 + q * 128 + col * 8) = *(const uint4*)(src + ks * 32);
    }
    __syncthreads();

    v4i srd0 = make_srd(hb0);
    v4i srd1 = make_srd(hb1);

    int tmax = 128 - 16 * grp;      // max seq length within this group's rows
    int rowl = w * 32;              // wave's local row base (0..96)
    int colg = jt * 16 + lrow;      // this lane's h-column
    int* bar = bars + grp * 64;     // per-group barrier counter (256 B apart)

    float creg[2][4];
#pragma unroll
    for (int m = 0; m < 2; ++m)
#pragma unroll
        for (int rg = 0; rg < 4; ++rg) creg[m][rg] = 0.0f;

    for (int t = 0; t < tmax; ++t) {
        int local_bs = 8 * (128 - t) - grp * 128;
        if (local_bs > 128) local_bs = 128;
        long tok0 = 4L * t * (257 - t) + grp * 128;     // token idx of this group's row 0
        v4i srd_r = (t & 1) ? srd1 : srd0;
        v4i srd_w = (t & 1) ? srd0 : srd1;
        bool wact = rowl < local_bs;

        // gx prefetch for this step (read-only, cached) — issued before the barrier spin
        unsigned int gxr[2][4][4];
        if (wact) {
#pragma unroll
            for (int m = 0; m < 2; ++m)
#pragma unroll
                for (int rg = 0; rg < 4; ++rg) {
                    int row = rowl + m * 16 + quad * 4 + rg;
                    bool act = row < local_bs;
                    long gb = (tok0 + row) * 2048;
#pragma unroll
                    for (int g = 0; g < 4; ++g)
                        gxr[m][g][rg] = act ? (unsigned int)gx[gb + g * 512 + colg] : 0u;
                }
        }

        // wait: all 32 group blocks finished step t-1
        if (t > 0) {
            if (tid == 0) {
                int target = 32 * t;
                while (__hip_atomic_load(bar, __ATOMIC_RELAXED, __HIP_MEMORY_SCOPE_AGENT) < target)
                    __builtin_amdgcn_s_sleep(1);
            }
            __syncthreads();
            asm volatile("" ::: "memory");
        }

        f32x4_t acc[2][4];
#pragma unroll
        for (int m = 0; m < 2; ++m)
#pragma unroll
            for (int g = 0; g < 4; ++g) acc[m][g] = (f32x4_t)(0.0f);

        if (t > 0 && wact) {
            // byte offsets into h buffer: row*1024 + ks*64 + quad*16, ks = 0..15
            int b0 = (grp * 128 + rowl + lrow) * 1024 + quad * 16;
            int b1 = b0 + 16 * 1024;
            union { v4i i; s16x8 h; } hreg[2][2][4];   // [slot][m][ksl]
#pragma unroll
            for (int ksl = 0; ksl < 4; ++ksl) {
                hreg[0][0][ksl].i = llvm_amdgcn_raw_buffer_load_v4i32(srd_r, b0 + ksl * 64, 0, CPOL_COH);
                hreg[0][1][ksl].i = llvm_amdgcn_raw_buffer_load_v4i32(srd_r, b1 + ksl * 64, 0, CPOL_COH);
            }
#pragma unroll
            for (int c = 0; c < 4; ++c) {
                if (c < 3) {
#pragma unroll
                    for (int ksl = 0; ksl < 4; ++ksl) {
                        hreg[(c + 1) & 1][0][ksl].i =
                            llvm_amdgcn_raw_buffer_load_v4i32(srd_r, b0 + (c + 1) * 256 + ksl * 64, 0, CPOL_COH);
                        hreg[(c + 1) & 1][1][ksl].i =
                            llvm_amdgcn_raw_buffer_load_v4i32(srd_r, b1 + (c + 1) * 256 + ksl * 64, 0, CPOL_COH);
                    }
                }
#pragma unroll
                for (int ksl = 0; ksl < 4; ++ksl) {
                    int ks = c * 4 + ksl;
                    s16x8 av0 = hreg[c & 1][0][ksl].h;
                    s16x8 av1 = hreg[c & 1][1][ksl].h;
#pragma unroll
                    for (int g = 0; g < 4; ++g) {
                        s16x8 b = *(const s16x8*)(Bs + (g * 16 + ks) * 512 + lane * 8);
                        acc[0][g] = MFMA16(av0, b, acc[0][g]);
                        acc[1][g] = MFMA16(av1, b, acc[1][g]);
                    }
                }
            }
        }

        if (wact) {
#pragma unroll
            for (int m = 0; m < 2; ++m) {
#pragma unroll
                for (int rg = 0; rg < 4; ++rg) {
                    int row = rowl + m * 16 + quad * 4 + rg;
                    float iv = acc[m][0][rg] + bf2f((unsigned short)gxr[m][0][rg]);
                    float fv = acc[m][1][rg] + bf2f((unsigned short)gxr[m][1][rg]);
                    float gv = acc[m][2][rg] + bf2f((unsigned short)gxr[m][2][rg]);
                    float ov = acc[m][3][rg] + bf2f((unsigned short)gxr[m][3][rg]);
                    float ig = 1.0f / (1.0f + __expf(-iv));
                    float fg = 1.0f / (1.0f + __expf(-fv));
                    float gt = 1.0f - 2.0f / (__expf(2.0f * gv) + 1.0f);
                    float og = 1.0f / (1.0f + __expf(-ov));
                    float cn = fg * creg[m][rg] + ig * gt;
                    creg[m][rg] = cn;
                    float hn = og * (1.0f - 2.0f / (__expf(2.0f * cn) + 1.0f));
                    if (row < local_bs) out[(tok0 + row) * 512 + colg] = hn;
                    // pack lane-pair (adjacent cols, same rows) into one u32 coherent store
                    unsigned int hv = (unsigned int)f2bf(hn);
                    unsigned int ov2 = (unsigned int)__shfl_xor((int)hv, 1, 64);
                    unsigned int hpair = (lane & 1) ? ((hv << 16) | ov2) : (hv | (ov2 << 16));
                    if (((lane & 1) == m) && (row < local_bs))
                        llvm_amdgcn_raw_buffer_store_i32(
                            (int)hpair, srd_w,
                            (grp * 128 + row) * 1024 + jt * 32 + (lrow >> 1) * 4, 0, CPOL_COH);
                }
            }
        }

        // arrive: h stores drained, then one relaxed RMW per block
        if (t < tmax - 1) {
            asm volatile("s_waitcnt vmcnt(0)" ::: "memory");
            __syncthreads();
            if (tid == 0)
                __hip_atomic_fetch_add(bar, 1, __ATOMIC_RELAXED, __HIP_MEMORY_SCOPE_AGENT);
        }
    }
}

// ---------------- host ----------------

extern "C" void kernel_launch(void* const* d_in, const int* in_sizes, int n_in,
                              void* d_out, int out_size, void* d_ws, size_t ws_size,
                              hipStream_t stream) {
    const float* embed = (const float*)d_in[0];
    const float* W_rel = (const float*)d_in[1];
    const float* b_rel = (const float*)d_in[2];
    const float* W_ih  = (const float*)d_in[3];
    const float* W_hh  = (const float*)d_in[4];
    const float* b_ih  = (const float*)d_in[5];
    const float* b_hh  = (const float*)d_in[6];
    const int* nodes = (const int*)d_in[7];
    const int* rels  = (const int*)d_in[8];
    int n_tok = in_sizes[7];
    float* out = (float*)d_out;

    char* ws = (char*)d_ws;
    size_t off = 0;
    auto alloc = [&](size_t bytes) -> void* {
        void* p = ws + off;
        off = (off + bytes + 255) & ~(size_t)255;
        return p;
    };
    unsigned short* gx    = (unsigned short*)alloc((size_t)n_tok * 2048 * 2);
    unsigned short* xg    = (unsigned short*)alloc((size_t)n_tok * 512 * 2);
    unsigned short* wih   = (unsigned short*)alloc((size_t)2048 * 512 * 2);
    unsigned short* whh   = (unsigned short*)alloc((size_t)2048 * 512 * 2);
    unsigned short* wrelT = (unsigned short*)alloc((size_t)RNUM * 512 * 512 * 2);
    unsigned short* wc    = (unsigned short*)alloc((size_t)RNUM * 2048 * 512 * 2);
    float* bcomp          = (float*)alloc((size_t)RNUM * 2048 * 4);
    unsigned short* h0    = (unsigned short*)alloc((size_t)1024 * 512 * 2);
    unsigned short* h1    = (unsigned short*)alloc((size_t)1024 * 512 * 2);
    int* perm             = (int*)alloc((size_t)n_tok * 4);
    int* bars             = (int*)alloc(RNUM * 64 * 4);
    int* cnt              = (int*)alloc(64);
    int* roff             = (int*)alloc(64);
    int* cur              = (int*)alloc(64);

    if (off > ws_size) return;  // workspace too small: fail loudly (out stays poisoned)

    hipMemsetAsync(cnt, 0, 64, stream);
    hipMemsetAsync(bars, 0, RNUM * 64 * 4, stream);

    int nw = 2048 * 512;
    k_convert2<<<dim3((nw + 255) / 256), dim3(256), 0, stream>>>(W_ih, W_hh, wih, whh, nw);
    k_bcomp<<<dim3(2048), dim3(256), 0, stream>>>(W_ih, b_rel, b_ih, b_hh, bcomp);
    k_transpose_wrel<<<dim3(8, 8, 8), dim3(256), 0, stream>>>(W_rel, wrelT);

    int nb = (n_tok + 255) / 256;
    k_count<<<dim3(nb), dim3(256), 0, stream>>>(rels, n_tok, cnt);
    k_offsets<<<dim3(1), dim3(1), 0, stream>>>(cnt, roff, cur);
    k_scatter<<<dim3(nb), dim3(256), 0, stream>>>(rels, n_tok, cur, perm);

    k_gather_x<<<dim3((n_tok + 3) / 4), dim3(256), 0, stream>>>(embed, nodes, perm, xg, n_tok);
    k_wcomp<<<dim3(32, 8, 8), dim3(256), 0, stream>>>(wih, wrelT, wc);

    int tilesA = (n_tok + 127) / 128 + RNUM;
    k_stageA2<<<dim3(16, tilesA), dim3(256), 0, stream>>>(xg, wc, bcomp, perm, roff, gx);

    k_scan_grp<<<dim3(256), dim3(256), 0, stream>>>(gx, whh, h0, h1, out, bars);
}